// Round 3
// 436.053 us; speedup vs baseline: 1.0258x; 1.0258x over previous
//
#include <hip/hip_runtime.h>
#include <hip/hip_bf16.h>
#include <cstddef>
#include <cstdint>

namespace {

constexpr int kN = 32;
constexpr int kC = 512;
constexpr int kHW = 3136;   // 56*56
constexpr int kL = 64;
constexpr int kCT = 512;
constexpr int kTok = 561;   // CT + 49
constexpr int kKcat = 576;  // 561 padded to 18*32

typedef float fx4 __attribute__((ext_vector_type(4)));
typedef float f32x4 __attribute__((ext_vector_type(4)));
typedef short short8 __attribute__((ext_vector_type(8)));
typedef unsigned int u32x2 __attribute__((ext_vector_type(2)));

// RNE f32->bf16 (single); memcpy = register reinterpret, bit_cast rejects HIP bf16 structs
static __device__ inline unsigned short bf16_1(float x) {
  __hip_bfloat16 h = __float2bfloat16(x);
  unsigned short u;
  __builtin_memcpy(&u, &h, 2);
  return u;
}
// RNE f32x2 -> packed 2x bf16 (low = a, high = b); compiler fuses to v_cvt_pk_bf16_f32
static __device__ inline unsigned pk2(float a, float b) {
  __hip_bfloat162 h2 = __float22bfloat162_rn(make_float2(a, b));
  unsigned u;
  __builtin_memcpy(&u, &h2, 4);
  return u;
}
static __device__ inline float bf2f(unsigned short h) {
  unsigned u = (unsigned)h << 16;
  float f;
  __builtin_memcpy(&f, &u, 4);
  return f;
}

// ---------------- prep: wcat16 (w_val folded into w_tok), cst, wtc16, denom=0, bcat pad ----------------
__global__ __launch_bounds__(256) void prep_kernel(
    const float* __restrict__ w_tok, const float* __restrict__ w_val,
    const float* __restrict__ b_val, const float* __restrict__ b_tok,
    const float* __restrict__ w_tc, unsigned short* __restrict__ wcat16,
    float* __restrict__ cst, unsigned short* __restrict__ wtc16,
    float* __restrict__ denom, unsigned short* __restrict__ bcat16) {
  int idx = blockIdx.x * 256 + threadIdx.x;
  if (idx < kCT * kKcat) {
    int d = idx / kKcat;
    int c = idx - d * kKcat;
    float v = 0.f;
    if (c < kCT) {
      int g = c >> 5, k = c & 31;
      const float* wt = w_tok + (size_t)d * kTok + g * 32;
      const float* wv = w_val + g * 1024 + k;
      float s = 0.f;
#pragma unroll
      for (int dp = 0; dp < 32; ++dp) s += wt[dp] * wv[dp * 32];
      v = s;
    } else if (c < kTok) {
      v = w_tok[(size_t)d * kTok + c];
    }
    wcat16[idx] = bf16_1(v);
    return;
  }
  idx -= kCT * kKcat;
  if (idx < kCT) {
    float s = b_tok[idx];
    for (int c = 0; c < kCT; ++c) s += w_tok[(size_t)idx * kTok + c] * b_val[c];
    cst[idx] = s;
    return;
  }
  idx -= kCT;
  if (idx < kL * kC) {
    wtc16[idx] = bf16_1(w_tc[idx]);
    return;
  }
  idx -= kL * kC;
  if (idx < kN * kL) {
    denom[idx] = 0.f;
    return;
  }
  idx -= kN * kL;
  if (idx < kN * kL * 15) {
    int n = idx / (kL * 15);
    int r = idx - n * (kL * 15);
    int l = r / 15;
    int k = kTok + (r - l * 15);
    bcat16[(size_t)n * kL * kKcat + (size_t)l * kKcat + k] = 0;
  }
}

// ---------------- K1: expT[n][l][p] = bf16(exp((w_tc@feat + b)/sqrt(C))), denom via atomics ----------------
// block 256 thr (4 waves), tile 64 l x 256 p, BK=64 c; grid (13, N). A direct from wtc16 (L2).
__global__ __launch_bounds__(256) void tc_gemm2_kernel(
    const float* __restrict__ feat, const unsigned short* __restrict__ wtc16,
    const float* __restrict__ b_tc, unsigned short* __restrict__ expT,
    float* __restrict__ denom) {
  const int n = blockIdx.y;
  const int pb = blockIdx.x * 256;
  const int tid = threadIdx.x;
  const int wave = tid >> 6, lane = tid & 63;
  const int quad = lane >> 4, l16 = lane & 15;
  __shared__ unsigned short Bs[256][72];
  __shared__ float bsm[64];
  __shared__ float denom_s[64];
  if (tid < 64) {
    bsm[tid] = b_tc[tid];
    denom_s[tid] = 0.f;
  }

  f32x4 acc[4][4];
#pragma unroll
  for (int i = 0; i < 4; ++i)
#pragma unroll
    for (int j = 0; j < 4; ++j) acc[i][j] = (f32x4){0.f, 0.f, 0.f, 0.f};

  const float* fb = feat + (size_t)n * kC * kHW;
  const int bc4 = (tid & 15) * 4, bpl0 = (tid >> 4) * 4;
  int pe_[4];
#pragma unroll
  for (int pass = 0; pass < 4; ++pass) {
    int pe = pb + bpl0 + pass * 64;
    pe_[pass] = pe < 3132 ? pe : 3132;
  }

  fx4 va[4][4], vb[4][4];
  auto LOADT = [&](int c0, fx4 (&v)[4][4]) {
#pragma unroll
    for (int pass = 0; pass < 4; ++pass) {
      const float* s = fb + (size_t)(c0 + bc4) * kHW + pe_[pass];
#pragma unroll
      for (int r = 0; r < 4; ++r) v[pass][r] = *(const fx4*)(s + (size_t)r * kHW);
    }
  };
  auto STORET = [&](fx4 (&v)[4][4]) {
#pragma unroll
    for (int pass = 0; pass < 4; ++pass) {
      int pl = bpl0 + pass * 4 * 16;
      (void)pl;
      int base = bpl0 + pass * 64;
#pragma unroll
      for (int j = 0; j < 4; ++j) {
        u32x2 w = {pk2(v[pass][0][j], v[pass][1][j]),
                   pk2(v[pass][2][j], v[pass][3][j])};
        *(u32x2*)&Bs[base + j][bc4] = w;
      }
    }
  };
  auto COMPUTE = [&](int c0) {
#pragma unroll
    for (int ks = 0; ks < 2; ++ks) {
      short8 a[4], b[4];
#pragma unroll
      for (int i = 0; i < 4; ++i)
        a[i] = *(const short8*)(wtc16 + (size_t)(i * 16 + l16) * kC + c0 +
                                ks * 32 + quad * 8);
#pragma unroll
      for (int j = 0; j < 4; ++j)
        b[j] = *(const short8*)&Bs[wave * 64 + j * 16 + l16][ks * 32 + quad * 8];
#pragma unroll
      for (int i = 0; i < 4; ++i)
#pragma unroll
        for (int j = 0; j < 4; ++j)
          acc[i][j] = __builtin_amdgcn_mfma_f32_16x16x32_bf16(a[i], b[j],
                                                              acc[i][j], 0, 0, 0);
    }
  };

  LOADT(0, va);
#pragma unroll
  for (int c0 = 0; c0 < kC; c0 += 128) {
    STORET(va);
    __syncthreads();
    LOADT(c0 + 64, vb);
    COMPUTE(c0);
    __syncthreads();
    STORET(vb);
    __syncthreads();
    if (c0 + 128 < kC) LOADT(c0 + 128, va);
    COMPUTE(c0 + 64);
    __syncthreads();
  }

  // epilogue: exp + bf16 store + denom partial sums
  const float inv = 0.04419417382415922f;  // 1/sqrt(512)
  unsigned short* eb = expT + (size_t)n * kL * kHW;
  float dsum[4][4];
#pragma unroll
  for (int ti = 0; ti < 4; ++ti)
#pragma unroll
    for (int r = 0; r < 4; ++r) dsum[ti][r] = 0.f;

#pragma unroll
  for (int ti = 0; ti < 4; ++ti) {
#pragma unroll
    for (int tj = 0; tj < 4; ++tj) {
      int pg = pb + wave * 64 + tj * 16 + l16;
      bool ok = pg < kHW;
#pragma unroll
      for (int r = 0; r < 4; ++r) {
        int l = ti * 16 + quad * 4 + r;
        float e = 0.f;
        if (ok) {
          float raw = (acc[ti][tj][r] + bsm[l]) * inv;
          unsigned short h = bf16_1(__expf(raw));
          eb[(size_t)l * kHW + pg] = h;
          e = bf2f(h);
        }
        dsum[ti][r] += e;
      }
    }
  }
  // reduce over the 16 lanes sharing the same l-set (l16 = p index)
#pragma unroll
  for (int off = 1; off < 16; off <<= 1) {
#pragma unroll
    for (int ti = 0; ti < 4; ++ti)
#pragma unroll
      for (int r = 0; r < 4; ++r) dsum[ti][r] += __shfl_xor(dsum[ti][r], off);
  }
  if (l16 == 0) {
#pragma unroll
    for (int ti = 0; ti < 4; ++ti)
#pragma unroll
      for (int r = 0; r < 4; ++r)
        atomicAdd(&denom_s[ti * 16 + quad * 4 + r], dsum[ti][r]);
  }
  __syncthreads();
  if (tid < 64) atomicAdd(&denom[n * 64 + tid], denom_s[tid]);
}

// ---------------- K3: part[s][n][l][c] = expT @ feat^T (unnormalized), A direct from expT ----------------
// block 256 thr, tile 64 l x 256 c, BK=64 p; grid (2, N, ksplit); klen % 64 == 0
__global__ __launch_bounds__(256) void m_gemm2_kernel(
    const float* __restrict__ feat, const unsigned short* __restrict__ expT,
    float* __restrict__ part, int klen) {
  const int cb = blockIdx.x * 256;
  const int n = blockIdx.y;
  const int s = blockIdx.z;
  const int p0s = s * klen;
  const int tid = threadIdx.x;
  const int wave = tid >> 6, lane = tid & 63;
  const int quad = lane >> 4, l16 = lane & 15;
  __shared__ unsigned short Bs[256][72];

  f32x4 acc[4][4];
#pragma unroll
  for (int i = 0; i < 4; ++i)
#pragma unroll
    for (int j = 0; j < 4; ++j) acc[i][j] = (f32x4){0.f, 0.f, 0.f, 0.f};

  const float* fb = feat + (size_t)n * kC * kHW;
  const unsigned short* ebase = expT + (size_t)n * kL * kHW;
  const int bkg = (tid >> 6) * 16, bcr = tid & 63;

  fx4 va[4][4], vb[4][4];
  auto LOADT = [&](int p0, fx4 (&v)[4][4]) {
#pragma unroll
    for (int pass = 0; pass < 4; ++pass) {
      const float* src = fb + (size_t)(cb + pass * 64 + bcr) * kHW + p0 + bkg;
#pragma unroll
      for (int u = 0; u < 4; ++u) v[pass][u] = *(const fx4*)(src + u * 4);
    }
  };
  auto STORET = [&](fx4 (&v)[4][4]) {
#pragma unroll
    for (int pass = 0; pass < 4; ++pass) {
#pragma unroll
      for (int u = 0; u < 4; ++u) {
        u32x2 w = {pk2(v[pass][u][0], v[pass][u][1]),
                   pk2(v[pass][u][2], v[pass][u][3])};
        *(u32x2*)&Bs[pass * 64 + bcr][bkg + u * 4] = w;
      }
    }
  };
  auto COMPUTE = [&](int p0) {
#pragma unroll
    for (int ks = 0; ks < 2; ++ks) {
      short8 a[4], b[4];
#pragma unroll
      for (int i = 0; i < 4; ++i)
        a[i] = *(const short8*)(ebase + (size_t)(i * 16 + l16) * kHW + p0 +
                                ks * 32 + quad * 8);
#pragma unroll
      for (int j = 0; j < 4; ++j)
        b[j] = *(const short8*)&Bs[wave * 64 + j * 16 + l16][ks * 32 + quad * 8];
#pragma unroll
      for (int i = 0; i < 4; ++i)
#pragma unroll
        for (int j = 0; j < 4; ++j)
          acc[i][j] = __builtin_amdgcn_mfma_f32_16x16x32_bf16(a[i], b[j],
                                                              acc[i][j], 0, 0, 0);
    }
  };

  const int nk = klen >> 6;  // number of 64-wide K-tiles
  LOADT(p0s, va);
  for (int t = 0; t < nk; t += 2) {
    const int p0 = p0s + t * 64;
    STORET(va);
    __syncthreads();
    const bool more1 = (t + 1) < nk;
    if (more1) LOADT(p0 + 64, vb);
    COMPUTE(p0);
    __syncthreads();
    if (more1) {
      STORET(vb);
      __syncthreads();
      if (t + 2 < nk) LOADT(p0 + 128, va);
      COMPUTE(p0 + 64);
      __syncthreads();
    }
  }

  float* ob = part + (size_t)(s * kN + n) * kL * kCT;
#pragma unroll
  for (int ti = 0; ti < 4; ++ti) {
#pragma unroll
    for (int tj = 0; tj < 4; ++tj) {
      int cg = cb + wave * 64 + tj * 16 + l16;
#pragma unroll
      for (int r = 0; r < 4; ++r) {
        int l = ti * 16 + quad * 4 + r;
        ob[(size_t)l * kCT + cg] = acc[ti][tj][r];
      }
    }
  }
}

// ---------------- reduce (part -> bcat16, normalized) + PosEncoder conv, merged ----------------
__global__ __launch_bounds__(256) void reduce_pos_kernel(
    const float* __restrict__ part, const float* __restrict__ denom,
    unsigned short* __restrict__ bcat16, const unsigned short* __restrict__ expT,
    const float* __restrict__ w3, const float* __restrict__ b3,
    const float* __restrict__ w1, const float* __restrict__ b1,
    float* __restrict__ pcl, int ksplit) {
  int idx = blockIdx.x * 256 + threadIdx.x;
  if (idx < kN * kL * kCT) {
    int n = idx >> 15;
    int r = idx & 32767;
    int l = r >> 9;
    int c = r & 511;
    float s = 0.f;
    for (int ss = 0; ss < ksplit; ++ss)
      s += part[(size_t)ss * (kN * kL * kCT) + idx];
    float si = 1.f / denom[n * 64 + l];
    bcat16[(size_t)n * kL * kKcat + (size_t)l * kKcat + c] = bf16_1(s * si);
    return;
  }
  idx -= kN * kL * kCT;
  if (idx >= kN * kL * 49) return;
  int n = idx / (kL * 49);
  int r = idx - n * (kL * 49);
  int lp = r / 49;
  int o = r - lp * 49;
  int y = o / 7, x = o - y * 7;
  const unsigned short* eb = expT + (size_t)n * kL * kHW;
  const float* dB = denom + n * 64;
  float a = 0.f;
#pragma unroll
  for (int dy = 0; dy < 3; ++dy) {
    int i = 2 * y - 1 + dy;
    if (i < 0 || i >= 14) continue;
#pragma unroll
    for (int dx = 0; dx < 3; ++dx) {
      int j = 2 * x - 1 + dx;
      if (j < 0 || j >= 14) continue;
      int t = 224 * i + 4 * j;
      int lsm = t & 63;
      int p = lp * 49 + (t >> 6);
      float e = bf2f(eb[(size_t)lsm * kHW + p]);
      a += w3[dy * 3 + dx] * (e / dB[lsm]);
    }
  }
  pcl[(size_t)n * kL * 49 + lp * 49 + o] = (a + b3[0]) * w1[0] + b1[0];
}

// ---------------- pos -> bcat16[n][l][512+d] (bf16) ----------------
__global__ __launch_bounds__(256) void pos_out2_kernel(
    const float* __restrict__ pcl, const float* __restrict__ wp,
    const float* __restrict__ bp, unsigned short* __restrict__ bcat16) {
  const int n = blockIdx.x;
  __shared__ float t[64 * 49];
  for (int i = threadIdx.x; i < 64 * 49; i += 256)
    t[i] = pcl[(size_t)n * 64 * 49 + i];
  __syncthreads();
  for (int o = threadIdx.x; o < 64 * 49; o += 256) {
    int l = o / 49, d = o - l * 49;
    float s = bp[d];
#pragma unroll 7
    for (int q = 0; q < 49; ++q) s += wp[d * 49 + q] * t[l * 49 + q];
    bcat16[(size_t)n * kL * kKcat + (size_t)l * kKcat + kCT + d] = bf16_1(s);
  }
}

// ---------------- K5: out[n][d][l] = cst[d] + wcat16[d,:] @ bcat16[n][l,:] ----------------
// No LDS, fragments direct from L2. block 256 thr, tile 64 d x 64 l; grid (8, N)
__global__ __launch_bounds__(256) void out_gemm2_kernel(
    const unsigned short* __restrict__ wcat16,
    const unsigned short* __restrict__ bcat16, const float* __restrict__ cst,
    float* __restrict__ out) {
  const int db = blockIdx.x * 64;
  const int n = blockIdx.y;
  const int tid = threadIdx.x;
  const int wave = tid >> 6, lane = tid & 63;
  const int quad = lane >> 4, l16 = lane & 15;
  __shared__ float csm[64];
  if (tid < 64) csm[tid] = cst[db + tid];
  __syncthreads();

  f32x4 acc[4];
#pragma unroll
  for (int j = 0; j < 4; ++j) acc[j] = (f32x4){0.f, 0.f, 0.f, 0.f};

  const unsigned short* ab = wcat16 + (size_t)(db + wave * 16 + l16) * kKcat;
  const unsigned short* bb = bcat16 + (size_t)n * kL * kKcat;
#pragma unroll
  for (int k0 = 0; k0 < kKcat; k0 += 32) {
    short8 a = *(const short8*)(ab + k0 + quad * 8);
    short8 b[4];
#pragma unroll
    for (int j = 0; j < 4; ++j)
      b[j] = *(const short8*)(bb + (size_t)(j * 16 + l16) * kKcat + k0 + quad * 8);
#pragma unroll
    for (int j = 0; j < 4; ++j)
      acc[j] = __builtin_amdgcn_mfma_f32_16x16x32_bf16(a, b[j], acc[j], 0, 0, 0);
  }

  float* ob = out + (size_t)n * kCT * kL;
#pragma unroll
  for (int tj = 0; tj < 4; ++tj) {
    int lg = tj * 16 + l16;
#pragma unroll
    for (int r = 0; r < 4; ++r) {
      int dl = wave * 16 + quad * 4 + r;
      ob[(size_t)(db + dl) * kL + lg] = acc[tj][r] + csm[dl];
    }
  }
}

}  // namespace

extern "C" void kernel_launch(void* const* d_in, const int* in_sizes, int n_in,
                              void* d_out, int out_size, void* d_ws,
                              size_t ws_size, hipStream_t stream) {
  (void)in_sizes; (void)n_in; (void)out_size;
  const float* feat  = (const float*)d_in[0];
  const float* w_tc  = (const float*)d_in[1];
  const float* b_tc  = (const float*)d_in[2];
  const float* w_val = (const float*)d_in[3];
  const float* b_val = (const float*)d_in[4];
  const float* w_ds3 = (const float*)d_in[5];
  const float* b_ds3 = (const float*)d_in[6];
  const float* w_ds1 = (const float*)d_in[7];
  const float* b_ds1 = (const float*)d_in[8];
  const float* w_pos = (const float*)d_in[9];
  const float* b_pos = (const float*)d_in[10];
  const float* w_tok = (const float*)d_in[11];
  const float* b_tok = (const float*)d_in[12];
  float* out = (float*)d_out;

  float* ws = (float*)d_ws;
  size_t off = 0;
  unsigned short* expT = (unsigned short*)(ws + off);   off += (size_t)kN * kL * kHW / 2;    // 3,211,264 f
  unsigned short* bcat16 = (unsigned short*)(ws + off); off += (size_t)kN * kL * kKcat / 2;  //   589,824 f
  unsigned short* wcat16 = (unsigned short*)(ws + off); off += (size_t)kCT * kKcat / 2;      //   147,456 f
  unsigned short* wtc16 = (unsigned short*)(ws + off);  off += (size_t)kL * kC / 2;          //    16,384 f
  float* cst = ws + off;   off += kCT;
  float* denom = ws + off; off += kN * kL;
  float* pcl = ws + off;   off += (size_t)kN * kL * 49;
  float* part = ws + off;  // ksplit * 1,048,576 f

  // workspace guard: 7-way K-split needs off + 7*kN*kL*kCT floats
  int ksplit = 7;
  if (ws_size < (off + (size_t)7 * kN * kL * kCT) * sizeof(float)) ksplit = 1;
  const int klen = kHW / ksplit;

  // prep: wcat16 + cst + wtc16 + denom=0 + bcat pad  (360,960 items)
  prep_kernel<<<1410, 256, 0, stream>>>(w_tok, w_val, b_val, b_tok, w_tc,
                                        wcat16, cst, wtc16, denom, bcat16);
  tc_gemm2_kernel<<<dim3(13, kN), 256, 0, stream>>>(feat, wtc16, b_tc, expT,
                                                    denom);
  m_gemm2_kernel<<<dim3(2, kN, ksplit), 256, 0, stream>>>(feat, expT, part,
                                                          klen);
  reduce_pos_kernel<<<4488, 256, 0, stream>>>(part, denom, bcat16, expT, w_ds3,
                                              b_ds3, w_ds1, b_ds1, pcl, ksplit);
  pos_out2_kernel<<<kN, 256, 0, stream>>>(pcl, w_pos, b_pos, bcat16);
  out_gemm2_kernel<<<dim3(8, kN), 256, 0, stream>>>(wcat16, bcat16, cst, out);
}